// Round 4
// baseline (718.550 us; speedup 1.0000x reference)
//
#include <hip/hip_runtime.h>
#include <hip/hip_bf16.h>
#include <cstdint>
#include <cstddef>

typedef __bf16 bf16_t;
typedef __bf16 bf16x8 __attribute__((ext_vector_type(8)));
typedef __bf16 bf16x4 __attribute__((ext_vector_type(4)));
typedef float  f32x4  __attribute__((ext_vector_type(4)));

static constexpr int Bb = 4, Ss = 1024, Ee = 1024, Hh = 32, Dd = 32;
static constexpr int Ntok = Bb * Ss;   // 4096
static constexpr int E3   = 3 * Ee;    // 3072
static constexpr float SCALE  = 0.17677669529663687f;   // 1/sqrt(32)
static constexpr float SCALE2 = 0.25506060570135506f;   // SCALE * log2(e)

__device__ __forceinline__ void gl_lds16(const void* g, void* l) {
  __builtin_amdgcn_global_load_lds(
      (const __attribute__((address_space(1))) void*)g,
      (__attribute__((address_space(3))) void*)l, 16, 0, 0);
}

// ---------------------------------------------------------------- mega-prep:
// regions: [0,12288) f32->bf16 conversions | [12288,12300) qkv bias concat |
// [12300,12316) bias_c | [12316,12444) colmean partials
__global__ __launch_bounds__(256) void prep(const float* __restrict__ x,  const float* __restrict__ qw,
                                            const float* __restrict__ kw, const float* __restrict__ vw,
                                            const float* __restrict__ inw,const float* __restrict__ ow,
                                            const float* __restrict__ fw,
                                            const float* __restrict__ qb, const float* __restrict__ kb,
                                            const float* __restrict__ vb, const float* __restrict__ ob,
                                            const float* __restrict__ fb,
                                            bf16_t* __restrict__ xb, bf16_t* __restrict__ wqkv,
                                            bf16_t* __restrict__ winb, bf16_t* __restrict__ wob,
                                            bf16_t* __restrict__ wfb,
                                            float* __restrict__ qkvb, float* __restrict__ bias_c,
                                            float* __restrict__ part) {
  const int bx = blockIdx.x, t = threadIdx.x;
  if (bx < 12288) {
    const int i = bx * 256 + t;
    const float* src; bf16_t* dst; int base;
    if      (i < 1048576) { src = x;   dst = xb;                       base = 0; }
    else if (i < 1310720) { src = qw;  dst = wqkv;                     base = 1048576; }
    else if (i < 1572864) { src = kw;  dst = wqkv + (size_t)Ee * Ee;   base = 1310720; }
    else if (i < 1835008) { src = vw;  dst = wqkv + (size_t)2*Ee*Ee;   base = 1572864; }
    else if (i < 2621440) { src = inw; dst = winb;                     base = 1835008; }
    else if (i < 2883584) { src = ow;  dst = wob;                      base = 2621440; }
    else                  { src = fw;  dst = wfb;                      base = 2883584; }
    const int j = i - base;
    const float4 v = *(const float4*)(src + (size_t)j * 4);
    bf16x4 o = {(bf16_t)v.x, (bf16_t)v.y, (bf16_t)v.z, (bf16_t)v.w};
    *(bf16x4*)(dst + (size_t)j * 4) = o;
  } else if (bx < 12300) {
    const int i = (bx - 12288) * 256 + t;
    qkvb[i] = (i < 1024) ? qb[i] : (i < 2048) ? kb[i - 1024] : vb[i - 2048];
  } else if (bx < 12316) {
    // bias_c[n] = fb[n] + sum_j fw[n][j]*ob[j]
    const int n = (bx - 12300) * 64 + (t >> 2), p = t & 3;
    const float* row = fw + (size_t)n * 1024 + p * 256;
    const float* obp = ob + p * 256;
    float s = 0.f;
    for (int j = 0; j < 256; ++j) s += row[j] * obp[j];
    s += __shfl_xor(s, 1);
    s += __shfl_xor(s, 2);
    if (p == 0) bias_c[n] = s + fb[n];
  } else {
    const int idx = bx - 12316;                 // 128 blocks
    const int sc = idx & 31, b = idx >> 5;
    const float* base = x + ((size_t)b * Ss + sc * 32) * Ee;
    for (int k = 0; k < 4; ++k) {
      const int e = t + k * 256;
      float s = 0.f;
      for (int i = 0; i < 32; ++i) s += base[(size_t)i * Ee + e];
      part[((size_t)sc * 4 + b) * Ee + e] = s;
    }
  }
}

// ---------------------------------------------------------------- phase chain tail (one block)
__global__ __launch_bounds__(1024) void phase_fin(const float* __restrict__ part,
                                                  const float* __restrict__ w1,
                                                  const float* __restrict__ b1,
                                                  const float* __restrict__ w2,
                                                  const float* __restrict__ b2,
                                                  float* __restrict__ phase) {
  __shared__ float xm[4096];
  __shared__ float hb[4096];
  const int t = threadIdx.x;
#pragma unroll
  for (int j = 0; j < 4; ++j) {
    const int idx = t + j * 1024;
    const int b = idx >> 10, e = idx & 1023;
    float s = 0.f;
    for (int sc = 0; sc < 32; ++sc) s += part[((size_t)sc * 4 + b) * 1024 + e];
    xm[idx] = s * (1.0f / 1024.0f);
  }
  __syncthreads();
  {
    const float* wr = w1 + (size_t)t * 1024;
    float a0 = 0.f, a1 = 0.f, a2 = 0.f, a3 = 0.f;
    for (int e = 0; e < 1024; ++e) {
      const float wv = wr[e];
      a0 += xm[e] * wv; a1 += xm[1024 + e] * wv;
      a2 += xm[2048 + e] * wv; a3 += xm[3072 + e] * wv;
    }
    const float bb = b1[t];
    hb[t]        = fmaxf(a0 + bb, 0.f);
    hb[1024 + t] = fmaxf(a1 + bb, 0.f);
    hb[2048 + t] = fmaxf(a2 + bb, 0.f);
    hb[3072 + t] = fmaxf(a3 + bb, 0.f);
  }
  __syncthreads();
  if (t < 128) {
    const int b = t >> 5, hh = t & 31;
    const float* hr = hb + b * 1024;
    const float* wr = w2 + (size_t)hh * 1024;
    float s = 0.f;
    for (int j = 0; j < 1024; ++j) s += hr[j] * wr[j];
    phase[t] = cosf(s + b2[hh]);
  }
}

// ---------------------------------------------------------------- bf16 1024x1024 transpose
__global__ __launch_bounds__(256) void transpose1024(const bf16_t* __restrict__ in,
                                                     bf16_t* __restrict__ out) {
  __shared__ bf16_t t[64][72];
  const int jt = threadIdx.x >> 2, k16 = (threadIdx.x & 3) * 16;
  const int r0 = blockIdx.y * 64, c0 = blockIdx.x * 64;
  const bf16x8 a = *(const bf16x8*)(in + (size_t)(r0 + jt) * 1024 + c0 + k16);
  const bf16x8 b = *(const bf16x8*)(in + (size_t)(r0 + jt) * 1024 + c0 + k16 + 8);
  *(bf16x8*)&t[jt][k16] = a;
  *(bf16x8*)&t[jt][k16 + 8] = b;
  __syncthreads();
  bf16x8 v0, v1;
#pragma unroll
  for (int m = 0; m < 8; ++m) v0[m] = t[k16 + m][jt];
#pragma unroll
  for (int m = 0; m < 8; ++m) v1[m] = t[k16 + 8 + m][jt];
  *(bf16x8*)(out + (size_t)(c0 + jt) * 1024 + r0 + k16) = v0;
  *(bf16x8*)(out + (size_t)(c0 + jt) * 1024 + r0 + k16 + 8) = v1;
}

// ---------------------------------------------------------------- GEMM: C = A @ Bt^T + bias (+epilogue)
// MODE 0: bf16 | 4: bf16 * phase (3072-wide C, cols<2048) | 5: fp32, split-K (A2/Bt2 for k>=1024)
template <int MODE>
__global__ __launch_bounds__(256) void gemm_bt(const bf16_t* __restrict__ A,
                                               const bf16_t* __restrict__ A2,
                                               const bf16_t* __restrict__ Bt,
                                               const bf16_t* __restrict__ Bt2,
                                               const float* __restrict__ bias,
                                               void* __restrict__ Cout,
                                               const float* __restrict__ phase,
                                               int K, int lda, int ldb, int ldc) {
  __shared__ bf16_t As[128 * 32];
  __shared__ bf16_t Bs[128 * 32];
  const int tid = threadIdx.x;
  const int w = tid >> 6, lane = tid & 63;
  const int nwg = gridDim.x * gridDim.y;     // always % 8 == 0 here
  int flat = blockIdx.y * gridDim.x + blockIdx.x;
  flat = (flat & 7) * (nwg >> 3) + (flat >> 3);
  const int m0 = (flat / gridDim.x) * 128, n0 = (flat % gridDim.x) * 128;
  const int wr = (w >> 1) * 64, wc = (w & 1) * 64;
  const int r_ld = lane >> 2, c_ld = (lane & 3) * 8;
  const int rr = lane & 15, kk8 = (lane >> 4) * 8;
  f32x4 acc[4][4];
#pragma unroll
  for (int m = 0; m < 4; ++m)
#pragma unroll
    for (int n = 0; n < 4; ++n) acc[m][n] = f32x4{0.f, 0.f, 0.f, 0.f};

  for (int kt = 0; kt < K; kt += 32) {
    const bf16_t* Ak = A;
    const bf16_t* Bk = Bt;
    int kk = kt;
    if constexpr (MODE == 5) {
      if (kt >= 1024) { Ak = A2; Bk = Bt2; kk = kt - 1024; }
    }
#pragma unroll
    for (int j = 0; j < 2; ++j) {
      const int r0 = w * 16 + j * 64;
      gl_lds16(Ak + (size_t)(m0 + r0 + r_ld) * lda + kk + c_ld, &As[r0 * 32]);
      gl_lds16(Bk + (size_t)(n0 + r0 + r_ld) * ldb + kk + c_ld, &Bs[r0 * 32]);
    }
    __syncthreads();
    bf16x8 af[4], bfr[4];
#pragma unroll
    for (int m = 0; m < 4; ++m) af[m] = *(const bf16x8*)&As[(wr + m * 16 + rr) * 32 + kk8];
#pragma unroll
    for (int n = 0; n < 4; ++n) bfr[n] = *(const bf16x8*)&Bs[(wc + n * 16 + rr) * 32 + kk8];
#pragma unroll
    for (int m = 0; m < 4; ++m)
#pragma unroll
      for (int n = 0; n < 4; ++n)
        acc[m][n] = __builtin_amdgcn_mfma_f32_16x16x32_bf16(af[m], bfr[n], acc[m][n], 0, 0, 0);
    __syncthreads();
  }

  const int rr4 = (lane >> 4) * 4, cc = lane & 15;
#pragma unroll
  for (int m = 0; m < 4; ++m) {
#pragma unroll
    for (int n = 0; n < 4; ++n) {
      const int gr0 = m0 + wr + m * 16 + rr4;
      const int gc = n0 + wc + n * 16 + cc;
      const float bb = bias ? bias[gc] : 0.f;
#pragma unroll
      for (int i = 0; i < 4; ++i) {
        const size_t idx = (size_t)(gr0 + i) * ldc + gc;
        float v = acc[m][n][i] + bb;
        if constexpr (MODE == 4) {
          if (gc < 2048) v *= phase[(((gr0 + i) >> 10) << 5) + ((gc >> 5) & 31)];
        }
        if constexpr (MODE == 5) ((float*)Cout)[idx] = v;
        else ((bf16_t*)Cout)[idx] = (bf16_t)v;
      }
    }
  }
}

// ---------------------------------------------------------------- reorg: V transpose + K fragment-order
// x<8:  Vt[bh][d][s] transpose (plain layout; XOR applied at attn stage time)
// x>=8: K2[bh][kt][n][r][g][8] fragment-order copy
__global__ __launch_bounds__(256) void reorg_kv(const bf16_t* __restrict__ Ksrc,
                                                const bf16_t* __restrict__ Vsrc, int rs,
                                                bf16_t* __restrict__ K2,
                                                bf16_t* __restrict__ Vt) {
  const int bh = blockIdx.y, b = bh >> 5, h = bh & 31;
  if (blockIdx.x < 8) {
    __shared__ bf16_t buf[128 * 33];
    const int s0 = blockIdx.x * 128;
    const bf16_t* in = Vsrc + ((size_t)b * Ss + s0) * rs + h * 32;
    for (int e = threadIdx.x; e < 128 * 32; e += 256) {
      const int s = e >> 5, d = e & 31;
      buf[s * 33 + d] = in[(size_t)s * rs + d];
    }
    __syncthreads();
    bf16_t* outp = Vt + (size_t)bh * 32768 + s0;
    for (int e = threadIdx.x; e < 128 * 32; e += 256) {
      const int d = e >> 7, s = e & 127;
      outp[(size_t)d * 1024 + s] = buf[s * 33 + d];
    }
  } else {
    const int xx = blockIdx.x - 8;                  // 0..15
    const int idx = xx * 2048 + threadIdx.x * 8;    // elem offset in [0,32768)
    const int kt = idx >> 11, rem = idx & 2047;
    const int n = rem >> 9, rem2 = rem & 511;
    const int r = rem2 >> 5, g = (rem2 >> 3) & 3;
    const int s = kt * 64 + n * 16 + r;
    const bf16x8 v = *(const bf16x8*)(Ksrc + ((size_t)b * Ss + s) * rs + h * 32 + g * 8);
    *(bf16x8*)(K2 + (size_t)bh * 32768 + idx) = v;
  }
}

// ---------------------------------------------------------------- fused attention
// 512 thr = 8 waves, 128 q-rows/block, grid (8,128). LDS = V (64KB, chunk-XOR) + P (8x2KB, XOR) = 80KB
// -> 2 blocks/CU. K fragments read from K2 global (coalesced 1KB/instr, L2-resident).
// Swapped QK^T (mfma(K,Q)): lane(g,r) holds P^T[key=n*16+4g+i][q=qrow0+r].
static constexpr int ATTN_LDS = 81920;

template <int WRITE_P>
__global__ __launch_bounds__(512) void attn_fused(const bf16_t* __restrict__ Qm, int rs,
                                                  const bf16_t* __restrict__ K2,
                                                  const bf16_t* __restrict__ Vt,
                                                  float* __restrict__ Pout,
                                                  bf16_t* __restrict__ ctx, float scale2) {
  extern __shared__ char smem[];
  char* Vl = smem;                                   // [32 d][128 chunks of 16B], chunk^= (d&7)
  const int tid = threadIdx.x, lane = tid & 63, w = tid >> 6;
  const int g = lane >> 4, r = lane & 15, rx = r & 7;
  char* myP = smem + 65536 + w * 2048;               // [16 q][8 chunks], chunk ^= (q&7)
  int flat = blockIdx.y * 8 + blockIdx.x;
  flat = (flat & 7) * 128 + (flat >> 3);             // XCD: 16 consecutive bh per XCD
  const int bh = flat >> 3, xb = flat & 7;
  const int b = bh >> 5, h = bh & 31;

  // stage V: wave w -> d-rows 4w..4w+3; linear LDS dest, XOR-permuted global source chunk
  {
    const bf16_t* vsrc = Vt + (size_t)bh * 32768;
#pragma unroll
    for (int rr2 = 0; rr2 < 4; ++rr2) {
      const int d = w * 4 + rr2;
#pragma unroll
      for (int c = 0; c < 2; ++c)
        gl_lds16(vsrc + d * 1024 + (((c * 64 + lane) ^ (d & 7)) * 8), Vl + d * 2048 + c * 1024);
    }
  }
  const int qrow0 = xb * 128 + w * 16;
  const bf16x8 qraw = *(const bf16x8*)(Qm + ((size_t)b * Ss + qrow0 + r) * rs + h * 32 + g * 8);
  bf16x8 qf;  // pre-scaled by SCALE*log2e -> use exp2
#pragma unroll
  for (int i = 0; i < 8; ++i) qf[i] = (bf16_t)((float)qraw[i] * scale2);

  const bf16_t* k2 = K2 + (size_t)bh * 32768;
  const int koff = r * 32 + g * 8;
  const f32x4 zero = {0.f, 0.f, 0.f, 0.f};
  float lsum = 0.f, rinv = 1.f;

  if constexpr (WRITE_P) {
    // pass 1: row sums (overlaps V staging)
    for (int kt = 0; kt < 16; ++kt) {
#pragma unroll
      for (int n = 0; n < 4; ++n) {
        const bf16x8 kf = *(const bf16x8*)(k2 + (kt * 4 + n) * 512 + koff);
        const f32x4 s = __builtin_amdgcn_mfma_f32_16x16x32_bf16(kf, qf, zero, 0, 0, 0);
#pragma unroll
        for (int i = 0; i < 4; ++i) lsum += exp2f(fminf(s[i], 80.f));
      }
    }
    lsum += __shfl_xor(lsum, 16);
    lsum += __shfl_xor(lsum, 32);
    rinv = 1.0f / lsum;
  }
  __syncthreads();  // V staged

  f32x4 acc2[2] = {zero, zero};  // ctx^T: acc2[dn][i] = ctx[q=qrow0+r][d=dn*16+4g+i]
  const size_t pbase = (size_t)bh * Ss * Ss;

  for (int kt = 0; kt < 16; ++kt) {
    float p[4][4];
#pragma unroll
    for (int n = 0; n < 4; ++n) {
      const bf16x8 kf = *(const bf16x8*)(k2 + (kt * 4 + n) * 512 + koff);
      const f32x4 s = __builtin_amdgcn_mfma_f32_16x16x32_bf16(kf, qf, zero, 0, 0, 0);
#pragma unroll
      for (int i = 0; i < 4; ++i) {
        float e = exp2f(fminf(s[i], 80.f));
        if constexpr (WRITE_P) e *= rinv;   // normalized everywhere
        else lsum += e;
        p[n][i] = e;
      }
      // P tile (bf16x4): logical chunk 2n+(g>>1), half g&1, row r, chunk ^= rx
      bf16x4 pw = {(bf16_t)p[n][0], (bf16_t)p[n][1], (bf16_t)p[n][2], (bf16_t)p[n][3]};
      *(bf16x4*)(myP + r * 128 + (((2 * n + (g >> 1)) ^ rx) << 4) + ((g & 1) << 3)) = pw;
      if constexpr (WRITE_P) {
        f32x4 w4 = {p[n][0], p[n][1], p[n][2], p[n][3]};
        *(f32x4*)&Pout[pbase + (size_t)(qrow0 + r) * Ss + kt * 64 + n * 16 + 4 * g] = w4;
      }
    }
    // PV: A = V^T d-rows, B = P^T -> acc2[dn] += V^T x P
#pragma unroll
    for (int c = 0; c < 2; ++c) {
      const bf16x8 pa = *(const bf16x8*)(myP + r * 128 + (((4 * c + g) ^ rx) << 4));
#pragma unroll
      for (int dn = 0; dn < 2; ++dn) {
        const int d = dn * 16 + r;
        const bf16x8 vf = *(const bf16x8*)(Vl + d * 2048 + (((kt * 8 + c * 4 + g) ^ rx) << 4));
        acc2[dn] = __builtin_amdgcn_mfma_f32_16x16x32_bf16(vf, pa, acc2[dn], 0, 0, 0);
      }
    }
  }

  if constexpr (!WRITE_P) {
    lsum += __shfl_xor(lsum, 16);
    lsum += __shfl_xor(lsum, 32);
    rinv = 1.0f / lsum;
  }
  // ctx store: reg-direct, 2x bf16x4 per lane
#pragma unroll
  for (int dn = 0; dn < 2; ++dn) {
    bf16x4 cv;
#pragma unroll
    for (int i = 0; i < 4; ++i)
      cv[i] = (bf16_t)(WRITE_P ? acc2[dn][i] : acc2[dn][i] * rinv);
    *(bf16x4*)&ctx[((size_t)b * Ss + qrow0 + r) * Ee + h * 32 + dn * 16 + 4 * g] = cv;
  }
}

// ================================================================ launcher
extern "C" void kernel_launch(void* const* d_in, const int* in_sizes, int n_in,
                              void* d_out, int out_size, void* d_ws, size_t ws_size,
                              hipStream_t stream) {
  const float* x     = (const float*)d_in[0];
  const float* q_w   = (const float*)d_in[1];
  const float* q_b   = (const float*)d_in[2];
  const float* k_w   = (const float*)d_in[3];
  const float* k_b   = (const float*)d_in[4];
  const float* v_w   = (const float*)d_in[5];
  const float* v_b   = (const float*)d_in[6];
  const float* ph_w1 = (const float*)d_in[7];
  const float* ph_b1 = (const float*)d_in[8];
  const float* ph_w2 = (const float*)d_in[9];
  const float* ph_b2 = (const float*)d_in[10];
  const float* in_w  = (const float*)d_in[11];
  const float* in_b  = (const float*)d_in[12];
  const float* out_w = (const float*)d_in[13];
  const float* out_b = (const float*)d_in[14];
  const float* fin_w = (const float*)d_in[15];
  const float* fin_b = (const float*)d_in[16];

  float* outp = (float*)d_out;
  float* attn_out = outp + (size_t)Ntok * Ee;

  char* ws = (char*)d_ws;
  size_t off = 0;
  auto alloc = [&](size_t bytes) -> void* {
    void* p = ws + off;
    off += (bytes + 255) & ~(size_t)255;
    return p;
  };
  bf16_t* x_bf  = (bf16_t*)alloc((size_t)Ntok * Ee * 2);
  bf16_t* wqkv  = (bf16_t*)alloc((size_t)E3 * Ee * 2);
  bf16_t* win   = (bf16_t*)alloc((size_t)E3 * Ee * 2);
  bf16_t* wout  = (bf16_t*)alloc((size_t)Ee * Ee * 2);
  bf16_t* wfin  = (bf16_t*)alloc((size_t)Ee * Ee * 2);
  bf16_t* woutT = (bf16_t*)alloc((size_t)Ee * Ee * 2);
  bf16_t* Wc    = (bf16_t*)alloc((size_t)Ee * Ee * 2);
  bf16_t* QKVb  = (bf16_t*)alloc((size_t)Ntok * E3 * 2);
  bf16_t* Vt    = (bf16_t*)alloc((size_t)128 * 32768 * 2);
  bf16_t* K2a   = (bf16_t*)alloc((size_t)128 * 32768 * 2);
  bf16_t* ctx   = (bf16_t*)alloc((size_t)Ntok * Ee * 2);
  bf16_t* qkv2  = (bf16_t*)alloc((size_t)Ntok * E3 * 2);
  bf16_t* v2t   = (bf16_t*)alloc((size_t)128 * 32768 * 2);
  bf16_t* K2b   = (bf16_t*)alloc((size_t)128 * 32768 * 2);
  bf16_t* ctx2  = (bf16_t*)alloc((size_t)Ntok * Ee * 2);
  float* part   = (float*)alloc((size_t)32 * 4 * 1024 * 4);
  float* phase  = (float*)alloc(128 * 4);
  float* qkvb   = (float*)alloc(3072 * 4);
  float* bias_c = (float*)alloc(1024 * 4);

  hipFuncSetAttribute((const void*)attn_fused<1>,
                      hipFuncAttributeMaxDynamicSharedMemorySize, ATTN_LDS);
  hipFuncSetAttribute((const void*)attn_fused<0>,
                      hipFuncAttributeMaxDynamicSharedMemorySize, ATTN_LDS);

  // 1. mega-prep (conversions, bias concat, bias_c, colmean partials)
  prep<<<12444, 256, 0, stream>>>(x, q_w, k_w, v_w, in_w, out_w, fin_w,
                                  q_b, k_b, v_b, out_b, fin_b,
                                  x_bf, wqkv, win, wout, wfin, qkvb, bias_c, part);
  // 2. phase chain tail
  phase_fin<<<1, 1024, 0, stream>>>(part, ph_w1, ph_b1, ph_w2, ph_b2, phase);
  // 3-4. Wc = fin_w @ out_w
  transpose1024<<<dim3(16, 16), 256, 0, stream>>>(wout, woutT);
  gemm_bt<0><<<dim3(8, 8), 256, 0, stream>>>(wfin, nullptr, woutT, nullptr, nullptr,
                                             Wc, nullptr, 1024, Ee, Ee, Ee);
  // 5. fused QKV projection (phase fused on Q,K columns)
  gemm_bt<4><<<dim3(24, 32), 256, 0, stream>>>(x_bf, nullptr, wqkv, nullptr, qkvb,
                                               QKVb, phase, 1024, Ee, Ee, E3);
  // 6. reorg K/V for attention 1
  reorg_kv<<<dim3(24, 128), 256, 0, stream>>>(QKVb + 1024, QKVb + 2048, E3, K2a, Vt);
  // 7. attention 1 (P -> d_out, fused PV)
  attn_fused<1><<<dim3(8, 128), 512, ATTN_LDS, stream>>>(QKVb, E3, K2a, Vt,
                                                         attn_out, ctx, SCALE2);
  // 8. in_proj
  gemm_bt<0><<<dim3(24, 32), 256, 0, stream>>>(ctx, nullptr, win, nullptr, in_b,
                                               qkv2, nullptr, 1024, Ee, Ee, E3);
  // 9. reorg K/V for attention 2
  reorg_kv<<<dim3(24, 128), 256, 0, stream>>>(qkv2 + 1024, qkv2 + 2048, E3, K2b, v2t);
  // 10. attention 2 (flash)
  attn_fused<0><<<dim3(8, 128), 512, ATTN_LDS, stream>>>(qkv2, E3, K2b, v2t,
                                                         nullptr, ctx2, SCALE2);
  // 11. fused out_proj + residual + final: outp = ctx2@Wc^T + ctx@fin_w^T + bias_c
  gemm_bt<5><<<dim3(8, 32), 256, 0, stream>>>(ctx2, ctx, Wc, wfin, bias_c,
                                              outp, nullptr, 2048, Ee, Ee, Ee);
}